// Round 1
// baseline (689.803 us; speedup 1.0000x reference)
//
#include <hip/hip_runtime.h>
#include <hip/hip_bf16.h>

typedef __attribute__((ext_vector_type(8))) short short8;
typedef __attribute__((ext_vector_type(4))) short short4v;
typedef __attribute__((ext_vector_type(4))) float f32x4;

#define S_LEN 2048
#define D_DIM 128
#define BM 64      // q rows per block
#define BN 64      // kv rows per tile
#define KST 136    // K lds row stride (bf16 elems): 128 + 8 pad -> 272B = 17*16
#define VST 72     // Vt lds row stride: 64 + 8 pad -> 144B = 9*16
#define PST 72     // P lds row stride

__device__ __forceinline__ short f2bf(float f) {
  __hip_bfloat16 h = __float2bfloat16(f);
  return __builtin_bit_cast(short, h);
}

extern "C" __global__ void __launch_bounds__(256, 1)
fa_fwd_kernel(const float* __restrict__ Qg, const float* __restrict__ Kg,
              const float* __restrict__ Vg, float* __restrict__ Og)
{
  const int bh  = blockIdx.y;
  const int m0  = blockIdx.x * BM;
  const int tid = threadIdx.x;
  const int wv  = tid >> 6;
  const int ln  = tid & 63;
  const int l15 = ln & 15;
  const int lhi = ln >> 4;

  __shared__ __align__(16) short Klds[BN * KST];
  __shared__ __align__(16) short Vlds[D_DIM * VST];   // transposed: [d][k]
  __shared__ __align__(16) short Plds[4][16 * PST];

  const size_t base = (size_t)bh * S_LEN * D_DIM;
  const float* Qb = Qg + base;
  const float* Kb = Kg + base;
  const float* Vb = Vg + base;
  float*       Ob = Og + base;

  const float scale = 0.08838834764831845f; // 1/sqrt(128)

  // ---- Q fragments in registers (bf16, pre-scaled) ----
  short8 qf[4];
  {
    const int qrow = m0 + wv * 16 + l15;
    const float* qsrc = Qb + (size_t)qrow * D_DIM + lhi * 8;
    #pragma unroll
    for (int kk = 0; kk < 4; ++kk) {
      f32x4 a = *(const f32x4*)(qsrc + kk * 32);
      f32x4 b = *(const f32x4*)(qsrc + kk * 32 + 4);
      short8 f;
      f[0] = f2bf(a[0] * scale); f[1] = f2bf(a[1] * scale);
      f[2] = f2bf(a[2] * scale); f[3] = f2bf(a[3] * scale);
      f[4] = f2bf(b[0] * scale); f[5] = f2bf(b[1] * scale);
      f[6] = f2bf(b[2] * scale); f[7] = f2bf(b[3] * scale);
      qf[kk] = f;
    }
  }

  const f32x4 fzero = {0.f, 0.f, 0.f, 0.f};
  f32x4 oacc[8];
  #pragma unroll
  for (int i = 0; i < 8; ++i) oacc[i] = fzero;
  float mrow[4] = {-INFINITY, -INFINITY, -INFINITY, -INFINITY};
  float lrow[4] = {0.f, 0.f, 0.f, 0.f};

  const int ntiles = blockIdx.x + 1;  // causal: kv tiles 0..bx
  for (int t = 0; t < ntiles; ++t) {
    const int kv0 = t * BN;
    __syncthreads();   // previous iter's PV done before LDS overwrite
    // ---- stage K (row-major) and V (transposed), fp32 -> bf16 ----
    #pragma unroll
    for (int i = 0; i < 8; ++i) {
      int idx = i * 256 + tid;
      // K: coalesced float4 loads
      int krow = idx >> 5;
      int kc4  = idx & 31;
      f32x4 kv4 = *(const f32x4*)(Kb + (size_t)(kv0 + krow) * D_DIM + kc4 * 4);
      short4v ks;
      ks[0] = f2bf(kv4[0]); ks[1] = f2bf(kv4[1]);
      ks[2] = f2bf(kv4[2]); ks[3] = f2bf(kv4[3]);
      *(short4v*)&Klds[krow * KST + kc4 * 4] = ks;
      // V: row varies per lane so transposed LDS writes are conflict-free
      int vrow = idx & 63;
      int vc4  = idx >> 6;
      f32x4 vv4 = *(const f32x4*)(Vb + (size_t)(kv0 + vrow) * D_DIM + vc4 * 4);
      #pragma unroll
      for (int j = 0; j < 4; ++j)
        Vlds[(vc4 * 4 + j) * VST + vrow] = f2bf(vv4[j]);
    }
    __syncthreads();

    // ---- S = (Q*scale) K^T : 4 col-chunks of 16 ----
    f32x4 sacc[4];
    #pragma unroll
    for (int nc = 0; nc < 4; ++nc) {
      sacc[nc] = fzero;
      #pragma unroll
      for (int kk = 0; kk < 4; ++kk) {
        short8 kf = *(const short8*)&Klds[(nc * 16 + l15) * KST + kk * 32 + lhi * 8];
        sacc[nc] = __builtin_amdgcn_mfma_f32_16x16x32_bf16(qf[kk], kf, sacc[nc], 0, 0, 0);
      }
    }

    // ---- causal mask (diagonal tile only) ----
    if (t == ntiles - 1) {
      #pragma unroll
      for (int nc = 0; nc < 4; ++nc)
        #pragma unroll
        for (int r = 0; r < 4; ++r) {
          int kcol = kv0 + nc * 16 + l15;
          int qrow = m0 + wv * 16 + lhi * 4 + r;
          if (kcol > qrow) sacc[nc][r] = -INFINITY;
        }
    }

    // ---- online softmax (rows live across 16-lane groups) ----
    float pmax[4] = {-INFINITY, -INFINITY, -INFINITY, -INFINITY};
    #pragma unroll
    for (int nc = 0; nc < 4; ++nc)
      #pragma unroll
      for (int r = 0; r < 4; ++r) pmax[r] = fmaxf(pmax[r], sacc[nc][r]);
    #pragma unroll
    for (int off = 1; off < 16; off <<= 1)
      #pragma unroll
      for (int r = 0; r < 4; ++r)
        pmax[r] = fmaxf(pmax[r], __shfl_xor(pmax[r], off));

    float alpha[4];
    #pragma unroll
    for (int r = 0; r < 4; ++r) {
      float mn = fmaxf(mrow[r], pmax[r]);
      alpha[r] = __expf(mrow[r] - mn);   // exp(-inf)=0 on first tile
      mrow[r] = mn;
    }

    float rsum[4] = {0.f, 0.f, 0.f, 0.f};
    #pragma unroll
    for (int nc = 0; nc < 4; ++nc)
      #pragma unroll
      for (int r = 0; r < 4; ++r) {
        float p = __expf(sacc[nc][r] - mrow[r]);  // masked -> exp(-inf)=0
        sacc[nc][r] = p;
        rsum[r] += p;
      }
    #pragma unroll
    for (int off = 1; off < 16; off <<= 1)
      #pragma unroll
      for (int r = 0; r < 4; ++r)
        rsum[r] += __shfl_xor(rsum[r], off);

    #pragma unroll
    for (int r = 0; r < 4; ++r) lrow[r] = lrow[r] * alpha[r] + rsum[r];
    #pragma unroll
    for (int dc = 0; dc < 8; ++dc)
      #pragma unroll
      for (int r = 0; r < 4; ++r) oacc[dc][r] *= alpha[r];

    // ---- P (C-layout) -> per-wave LDS -> A-fragment layout ----
    short* pw = &Plds[wv][0];
    #pragma unroll
    for (int nc = 0; nc < 4; ++nc)
      #pragma unroll
      for (int r = 0; r < 4; ++r)
        pw[(lhi * 4 + r) * PST + nc * 16 + l15] = f2bf(sacc[nc][r]);

    __syncthreads();  // order P writes before P reads (also keeps waves tile-synced)

    // ---- O += P V ----
    #pragma unroll
    for (int kk = 0; kk < 2; ++kk) {
      short8 pf = *(const short8*)&pw[l15 * PST + kk * 32 + lhi * 8];
      #pragma unroll
      for (int dc = 0; dc < 8; ++dc) {
        short8 vf = *(const short8*)&Vlds[(dc * 16 + l15) * VST + kk * 32 + lhi * 8];
        oacc[dc] = __builtin_amdgcn_mfma_f32_16x16x32_bf16(pf, vf, oacc[dc], 0, 0, 0);
      }
    }
  }

  // ---- epilogue: O / l ----
  float inv[4];
  #pragma unroll
  for (int r = 0; r < 4; ++r) inv[r] = 1.0f / lrow[r];
  #pragma unroll
  for (int dc = 0; dc < 8; ++dc)
    #pragma unroll
    for (int r = 0; r < 4; ++r)
      Ob[(size_t)(m0 + wv * 16 + lhi * 4 + r) * D_DIM + dc * 16 + l15] =
          oacc[dc][r] * inv[r];
}

extern "C" void kernel_launch(void* const* d_in, const int* in_sizes, int n_in,
                              void* d_out, int out_size, void* d_ws, size_t ws_size,
                              hipStream_t stream) {
  const float* Q = (const float*)d_in[0];
  const float* K = (const float*)d_in[1];
  const float* V = (const float*)d_in[2];
  float* O = (float*)d_out;
  dim3 grid(S_LEN / BM, 32 /* B*H */);
  dim3 block(256);
  fa_fwd_kernel<<<grid, block, 0, stream>>>(Q, K, V, O);
}

// Round 2
// 110.059 us; speedup vs baseline: 6.2676x; 6.2676x over previous
//
#include <hip/hip_runtime.h>
#include <hip/hip_bf16.h>

typedef __attribute__((ext_vector_type(8))) short short8;
typedef __attribute__((ext_vector_type(4))) short short4v;
typedef __attribute__((ext_vector_type(4))) float f32x4;

#define S_LEN 2048
#define D_DIM 128
#define BM 128     // q rows per block (8 waves x 16 rows)
#define BN 64      // kv rows per tile
#define NW 8       // waves per block
#define KST 136    // K lds row stride (bf16): 272B = 17*16 -> 2-way bank alias (free)
#define VST 72     // Vt lds row stride: 144B = 9*16 -> 2-way
#define PST 72     // P lds row stride

__device__ __forceinline__ short f2bf(float f) {
  __hip_bfloat16 h = __float2bfloat16(f);
  return __builtin_bit_cast(short, h);
}

extern "C" __global__ void __launch_bounds__(512, 2)
fa_fwd_kernel(const float* __restrict__ Qg, const float* __restrict__ Kg,
              const float* __restrict__ Vg, float* __restrict__ Og)
{
  const int bh = blockIdx.x;                       // b*h fastest -> XCD = bh%8 (L2 locality)
  const int qt = (int)(gridDim.y - 1) - (int)blockIdx.y;  // heavy q-tiles dispatch first
  const int m0 = qt * BM;
  const int tid = threadIdx.x;
  const int wv  = tid >> 6;
  const int ln  = tid & 63;
  const int l15 = ln & 15;
  const int lhi = ln >> 4;

  __shared__ __align__(16) short Klds[2][BN * KST];     // 2 x 17.0 KB
  __shared__ __align__(16) short Vlds[2][D_DIM * VST];  // 2 x 18.0 KB, transposed [d][k]
  __shared__ __align__(16) short Plds[NW][16 * PST];    // 18.0 KB, per-wave

  const size_t base = (size_t)bh * S_LEN * D_DIM;
  const float* Qb = Qg + base;
  const float* Kb = Kg + base;
  const float* Vb = Vg + base;
  float*       Ob = Og + base;

  const float scale = 0.08838834764831845f; // 1/sqrt(128)

  // ---- Q fragments in registers (bf16, pre-scaled) ----
  short8 qf[4];
  {
    const int qrow = m0 + wv * 16 + l15;
    const float* qsrc = Qb + (size_t)qrow * D_DIM + lhi * 8;
    #pragma unroll
    for (int kk = 0; kk < 4; ++kk) {
      f32x4 a = *(const f32x4*)(qsrc + kk * 32);
      f32x4 b = *(const f32x4*)(qsrc + kk * 32 + 4);
      short8 f;
      f[0] = f2bf(a[0] * scale); f[1] = f2bf(a[1] * scale);
      f[2] = f2bf(a[2] * scale); f[3] = f2bf(a[3] * scale);
      f[4] = f2bf(b[0] * scale); f[5] = f2bf(b[1] * scale);
      f[6] = f2bf(b[2] * scale); f[7] = f2bf(b[3] * scale);
      qf[kk] = f;
    }
  }

  // ---- staging helpers (512 threads: 4 float4 of K + 4 of V per thread) ----
  auto load_tile = [&](int t, f32x4* kr, f32x4* vr) {
    const float* Kt = Kb + (size_t)t * BN * D_DIM;
    const float* Vt = Vb + (size_t)t * BN * D_DIM;
    #pragma unroll
    for (int i = 0; i < 4; ++i) {
      int idx = i * 512 + tid;
      kr[i] = *(const f32x4*)(Kt + (size_t)(idx >> 5) * D_DIM + (idx & 31) * 4);
      vr[i] = *(const f32x4*)(Vt + (size_t)(idx & 63) * D_DIM + (idx >> 6) * 4);
    }
  };
  auto store_tile = [&](int buf, const f32x4* kr, const f32x4* vr) {
    #pragma unroll
    for (int i = 0; i < 4; ++i) {
      int idx = i * 512 + tid;
      short4v ks;
      ks[0] = f2bf(kr[i][0]); ks[1] = f2bf(kr[i][1]);
      ks[2] = f2bf(kr[i][2]); ks[3] = f2bf(kr[i][3]);
      *(short4v*)&Klds[buf][(idx >> 5) * KST + (idx & 31) * 4] = ks;
      #pragma unroll
      for (int j = 0; j < 4; ++j)
        Vlds[buf][((idx >> 6) * 4 + j) * VST + (idx & 63)] = f2bf(vr[i][j]);
    }
  };

  const f32x4 fzero = {0.f, 0.f, 0.f, 0.f};
  f32x4 oacc[8];
  #pragma unroll
  for (int i = 0; i < 8; ++i) oacc[i] = fzero;
  float mrow[4] = {-INFINITY, -INFINITY, -INFINITY, -INFINITY};
  float lrow[4] = {0.f, 0.f, 0.f, 0.f};

  const int ntiles = (m0 + BM - 1) / BN + 1;  // = 2*qt + 2 (causal)
  const int wrow_lo = m0 + wv * 16;           // wave's first q row
  short* pw = &Plds[wv][0];

  // prologue: stage tile 0
  {
    f32x4 kr[4], vr[4];
    load_tile(0, kr, vr);
    store_tile(0, kr, vr);
  }
  __syncthreads();

  int cur = 0;
  for (int t = 0; t < ntiles; ++t) {
    const int kv0 = t * BN;
    const bool pf = (t + 1 < ntiles);
    f32x4 kr2[4], vr2[4];
    if (pf) load_tile(t + 1, kr2, vr2);   // issue early: latency hides under compute

    const short* Kl = Klds[cur];
    const short* Vl = Vlds[cur];

    if (kv0 <= wrow_lo + 15) {   // wave-uniform: skip fully-masked diagonal sub-tiles
      // ---- S = (Q*scale) K^T ----
      f32x4 sacc[4];
      #pragma unroll
      for (int nc = 0; nc < 4; ++nc) {
        sacc[nc] = fzero;
        #pragma unroll
        for (int kk = 0; kk < 4; ++kk) {
          short8 kf = *(const short8*)&Kl[(nc * 16 + l15) * KST + kk * 32 + lhi * 8];
          sacc[nc] = __builtin_amdgcn_mfma_f32_16x16x32_bf16(qf[kk], kf, sacc[nc], 0, 0, 0);
        }
      }

      // ---- causal mask (only tiles that touch this wave's diagonal) ----
      if (kv0 + BN - 1 > wrow_lo) {
        #pragma unroll
        for (int nc = 0; nc < 4; ++nc)
          #pragma unroll
          for (int r = 0; r < 4; ++r) {
            int kcol = kv0 + nc * 16 + l15;
            int qrow = wrow_lo + lhi * 4 + r;
            if (kcol > qrow) sacc[nc][r] = -INFINITY;
          }
      }

      // ---- online softmax ----
      float pmax[4] = {-INFINITY, -INFINITY, -INFINITY, -INFINITY};
      #pragma unroll
      for (int nc = 0; nc < 4; ++nc)
        #pragma unroll
        for (int r = 0; r < 4; ++r) pmax[r] = fmaxf(pmax[r], sacc[nc][r]);
      #pragma unroll
      for (int off = 1; off < 16; off <<= 1)
        #pragma unroll
        for (int r = 0; r < 4; ++r)
          pmax[r] = fmaxf(pmax[r], __shfl_xor(pmax[r], off));

      float alpha[4];
      #pragma unroll
      for (int r = 0; r < 4; ++r) {
        float mn = fmaxf(mrow[r], pmax[r]);
        alpha[r] = __expf(mrow[r] - mn);
        mrow[r] = mn;
      }

      float rsum[4] = {0.f, 0.f, 0.f, 0.f};
      #pragma unroll
      for (int nc = 0; nc < 4; ++nc)
        #pragma unroll
        for (int r = 0; r < 4; ++r) {
          float p = __expf(sacc[nc][r] - mrow[r]);
          sacc[nc][r] = p;
          rsum[r] += p;
        }
      #pragma unroll
      for (int off = 1; off < 16; off <<= 1)
        #pragma unroll
        for (int r = 0; r < 4; ++r)
          rsum[r] += __shfl_xor(rsum[r], off);

      #pragma unroll
      for (int r = 0; r < 4; ++r) lrow[r] = lrow[r] * alpha[r] + rsum[r];
      #pragma unroll
      for (int dc = 0; dc < 8; ++dc)
        #pragma unroll
        for (int r = 0; r < 4; ++r) oacc[dc][r] *= alpha[r];

      // ---- P (C-layout) -> per-wave LDS -> A-fragment layout (wave-local, no barrier) ----
      #pragma unroll
      for (int nc = 0; nc < 4; ++nc)
        #pragma unroll
        for (int r = 0; r < 4; ++r)
          pw[(lhi * 4 + r) * PST + nc * 16 + l15] = f2bf(sacc[nc][r]);

      // ---- O += P V ----
      #pragma unroll
      for (int kk = 0; kk < 2; ++kk) {
        short8 pfr = *(const short8*)&pw[l15 * PST + kk * 32 + lhi * 8];
        #pragma unroll
        for (int dc = 0; dc < 8; ++dc) {
          short8 vf = *(const short8*)&Vl[(dc * 16 + l15) * VST + kk * 32 + lhi * 8];
          oacc[dc] = __builtin_amdgcn_mfma_f32_16x16x32_bf16(pfr, vf, oacc[dc], 0, 0, 0);
        }
      }
    }

    if (pf) store_tile(cur ^ 1, kr2, vr2);  // convert + LDS-write late (loads have landed)
    __syncthreads();                        // buf[cur^1] ready; everyone done with buf[cur]
    cur ^= 1;
  }

  // ---- epilogue: O / l ----
  float inv[4];
  #pragma unroll
  for (int r = 0; r < 4; ++r) inv[r] = 1.0f / lrow[r];
  #pragma unroll
  for (int dc = 0; dc < 8; ++dc)
    #pragma unroll
    for (int r = 0; r < 4; ++r)
      Ob[(size_t)(wrow_lo + lhi * 4 + r) * D_DIM + dc * 16 + l15] =
          oacc[dc][r] * inv[r];
}

extern "C" void kernel_launch(void* const* d_in, const int* in_sizes, int n_in,
                              void* d_out, int out_size, void* d_ws, size_t ws_size,
                              hipStream_t stream) {
  const float* Q = (const float*)d_in[0];
  const float* K = (const float*)d_in[1];
  const float* V = (const float*)d_in[2];
  float* O = (float*)d_out;
  dim3 grid(32 /* B*H */, S_LEN / BM);
  dim3 block(512);
  fa_fwd_kernel<<<grid, block, 0, stream>>>(Q, K, V, O);
}